// Round 1
// baseline (208.347 us; speedup 1.0000x reference)
//
#include <hip/hip_runtime.h>
#include <hip/hip_bf16.h>

// N=8192 rows, BD=64 code dim, CD=512 channel dim
#define NN 8192
#define BD 64
#define CDIM 512

typedef __attribute__((ext_vector_type(4))) float f32x4;
typedef __attribute__((ext_vector_type(4))) unsigned int u32x4;
typedef __attribute__((ext_vector_type(8))) __bf16 bf16x8;

// Fragment-major layouts (elems = unsigned short), frag = 512 ushorts = 1 KB:
//  adjF frag(it,kt): it=i/16 [0,512), kt=k/32 [0,256): off=(it*256+kt)*512+lane*8
//    lane=q*16+m holds adj[it*16+m][kt*32+q*8 .. +7]   (A-operand layout)
//  fcF  frag(nt,kt): nt=n/16 [0,32), kt=k/32 [0,256):  off=(nt*256+kt)*512+lane*8
//    lane holds fc2[kt*32+q*8 .. +7][nt*16+m]          (B-operand layout)
//  cbnF frag(it,ct): off=(it*16+ct)*512+lane*8  (A) ;  WF frag(nt,ct): off=(nt*16+ct)*512+lane*8 (B)

static __device__ __forceinline__ unsigned short f2bf(float x) {
    unsigned int u = __float_as_uint(x);
    u += 0x7fffu + ((u >> 16) & 1u);   // RTNE
    return (unsigned short)(u >> 16);
}

static __device__ __forceinline__ f32x4 mfma16(u32x4 a, u32x4 b, f32x4 c) {
    return __builtin_amdgcn_mfma_f32_16x16x32_bf16(
        __builtin_bit_cast(bf16x8, a), __builtin_bit_cast(bf16x8, b), c, 0, 0, 0);
}

static __device__ __forceinline__ u32x4 cvt8(const float* __restrict__ p) {
    float4 a = *(const float4*)p;
    float4 b = *(const float4*)(p + 4);
    u32x4 r;
    r.x = (unsigned)f2bf(a.x) | ((unsigned)f2bf(a.y) << 16);
    r.y = (unsigned)f2bf(a.z) | ((unsigned)f2bf(a.w) << 16);
    r.z = (unsigned)f2bf(b.x) | ((unsigned)f2bf(b.y) << 16);
    r.w = (unsigned)f2bf(b.z) | ((unsigned)f2bf(b.w) << 16);
    return r;
}

// async global->LDS DMA, 16B/lane. LDS dest = wave-uniform base + lane*16.
// CK-style addrspace casts via integer round-trip (generic LDS ptr low 32 bits = LDS offset).
static __device__ __forceinline__ void glds16(const unsigned short* g, const unsigned short* l) {
    __builtin_amdgcn_global_load_lds(
        (const __attribute__((address_space(1))) unsigned int*)(unsigned long long)g,
        (__attribute__((address_space(3))) unsigned int*)(unsigned int)(unsigned long long)l,
        16, 0, 0);
}

// adj = (max(1 - |2*dot - si - sj|/64, 0))^1.4
static __device__ __forceinline__ float adj_fn(float dot, float sij) {
    float x = fabsf(fmaf(2.0f, dot, -sij));
    float base = fmaxf(fmaf(-0.015625f, x, 1.0f), 0.0f);
    return exp2f(1.4f * __log2f(base));   // pow(0,1.4)=0 via -inf
}

// ---------------- prep: bbn -> bf16 (row-major), row sums s ----------------
__global__ void prep_kernel(const float* __restrict__ bbn,
                            unsigned short* __restrict__ tbf,
                            float* __restrict__ s) {
    int gid = blockIdx.x * blockDim.x + threadIdx.x;  // 16 threads/row
    int row = gid >> 4;
    int part = gid & 15;
    float4 v = *(const float4*)(bbn + row * BD + part * 4);
    ushort4 o;
    o.x = f2bf(v.x); o.y = f2bf(v.y); o.z = f2bf(v.z); o.w = f2bf(v.w);
    *(ushort4*)(tbf + row * BD + part * 4) = o;
    float ps = v.x + v.y + v.z + v.w;
    ps += __shfl_xor(ps, 1); ps += __shfl_xor(ps, 2);
    ps += __shfl_xor(ps, 4); ps += __shfl_xor(ps, 8);
    if (part == 0) s[row] = ps;
}

// ---------------- prep_cbn: cbn -> A-frag-major bf16 ----------------
__global__ __launch_bounds__(256) void prep_cbn_kernel(const float* __restrict__ cbn,
                                                       unsigned short* __restrict__ cbnF) {
    const int lane = threadIdx.x & 63;
    const int wave = threadIdx.x >> 6;
    const int m = lane & 15, q = lane >> 4;
#pragma unroll
    for (int t = 0; t < 4; ++t) {
        int f = blockIdx.x * 16 + wave * 4 + t;   // 8192 frags
        int it = f >> 4, ct = f & 15;
        u32x4 v = cvt8(cbn + (size_t)(it * 16 + m) * CDIM + ct * 32 + q * 8);
        *(u32x4*)(cbnF + (size_t)f * 512 + lane * 8) = v;
    }
}

// ---------------- prep_w: W -> B-frag-major bf16 ----------------
__global__ __launch_bounds__(256) void prep_w_kernel(const float* __restrict__ W,
                                                     unsigned short* __restrict__ WF) {
    const int lane = threadIdx.x & 63;
    const int wave = threadIdx.x >> 6;
    const int m = lane & 15, q = lane >> 4;
    int f = blockIdx.x * 4 + wave;   // 512 frags
    int nt = f >> 4, ct = f & 15;
    u32x4 v = cvt8(W + (size_t)(nt * 16 + m) * CDIM + ct * 32 + q * 8);
    *(u32x4*)(WF + (size_t)f * 512 + lane * 8) = v;
}

// ---------------- scoredeg: adjF = frag-major bf16 adj, d[i] = row sums ----------------
// grid (128 i-tiles, 16 j-chunks of 512) = 2048 blocks -> 8 blocks/CU.
// Double-buffered LDS: ONE barrier per 64-j tile (write p | barrier | read p || write p^1 ...).
__global__ __launch_bounds__(256) void scoredeg_kernel(const unsigned short* __restrict__ tbf,
                                                       const float* __restrict__ s,
                                                       float* __restrict__ d,
                                                       unsigned short* __restrict__ adjF) {
    const int lane = threadIdx.x & 63;
    const int wave = threadIdx.x >> 6;   // 0..3
    const int m = lane & 15, q = lane >> 4;
    const int i0 = blockIdx.x * 64;
    const int jbase = blockIdx.y * 512;

    __shared__ __align__(16) unsigned short Slds[2][64][72];  // 18.4 KB

    u32x4 afr[4][2];
    float si[4][4];
#pragma unroll
    for (int mt = 0; mt < 4; ++mt) {
#pragma unroll
        for (int ks = 0; ks < 2; ++ks)
            afr[mt][ks] = *(const u32x4*)(tbf + (i0 + mt * 16 + m) * BD + ks * 32 + q * 8);
#pragma unroll
        for (int r = 0; r < 4; ++r) si[mt][r] = s[i0 + mt * 16 + q * 4 + r];
    }
    float dsum[4][4] = {};

    // prefetch iter-0 B operand
    int jw = jbase + wave * 16;
    u32x4 b0 = *(const u32x4*)(tbf + (jw + m) * BD + q * 8);
    u32x4 b1 = *(const u32x4*)(tbf + (jw + m) * BD + 32 + q * 8);
    float sj = s[jw + m];

    for (int it8 = 0; it8 < 8; ++it8) {
        const int J = jbase + it8 * 64;
        const int p = it8 & 1;
        f32x4 c[4];
#pragma unroll
        for (int mt = 0; mt < 4; ++mt) {
            c[mt] = f32x4{0.f, 0.f, 0.f, 0.f};
            c[mt] = mfma16(afr[mt][0], b0, c[mt]);
            c[mt] = mfma16(afr[mt][1], b1, c[mt]);
        }
        // prefetch next iter's B while transform runs
        int jn = (it8 < 7) ? J + 64 + wave * 16 : jbase + wave * 16;
        u32x4 nb0 = *(const u32x4*)(tbf + (jn + m) * BD + q * 8);
        u32x4 nb1 = *(const u32x4*)(tbf + (jn + m) * BD + 32 + q * 8);
        float nsj = s[jn + m];
#pragma unroll
        for (int mt = 0; mt < 4; ++mt)
#pragma unroll
            for (int r = 0; r < 4; ++r) {
                float a = adj_fn(c[mt][r], si[mt][r] + sj);
                dsum[mt][r] += a;
                Slds[p][mt * 16 + q * 4 + r][wave * 16 + m] = f2bf(a);
            }
        __syncthreads();
        // frag store: wave w -> it-tile (i0/16 + w), k-tiles J/32 + {0,1}
#pragma unroll
        for (int ktl = 0; ktl < 2; ++ktl) {
            u32x4 v = *(const u32x4*)(&Slds[p][wave * 16 + m][ktl * 32 + q * 8]);
            *(u32x4*)(adjF + ((size_t)((i0 >> 4) + wave) * 256 + (J >> 5) + ktl) * 512 + lane * 8) = v;
        }
        b0 = nb0; b1 = nb1; sj = nsj;
    }

#pragma unroll
    for (int mt = 0; mt < 4; ++mt)
#pragma unroll
        for (int r = 0; r < 4; ++r) {
            float v = dsum[mt][r];
            v += __shfl_xor(v, 1); v += __shfl_xor(v, 2);
            v += __shfl_xor(v, 4); v += __shfl_xor(v, 8);
            if (m == 0) atomicAdd(&d[i0 + mt * 16 + q * 4 + r], v);
        }
}

// ---------------- dinv ----------------
__global__ void dinv_kernel(const float* __restrict__ d, float* __restrict__ dinv) {
    int i = blockIdx.x * 256 + threadIdx.x;
    dinv[i] = rsqrtf(d[i] + 1e-8f);
}

// ---------------- fc: fcF = frag-major bf16(dinv[i]*(cbnF @ WF + b)) ----------------
__global__ __launch_bounds__(256) void fc_kernel(const unsigned short* __restrict__ cbnF,
                                                 const unsigned short* __restrict__ WF,
                                                 const float* __restrict__ bias,
                                                 const float* __restrict__ dinv,
                                                 unsigned short* __restrict__ fcF) {
    const int lane = threadIdx.x & 63;
    const int wave = threadIdx.x >> 6;
    const int m = lane & 15, q = lane >> 4;
    const int i0 = blockIdx.x * 64;
    const int ntg = blockIdx.y * 4 + wave;   // 0..31

    const u32x4* Ag = (const u32x4*)cbnF;
    const u32x4* Bg = (const u32x4*)WF;

    f32x4 acc[4] = {};
#pragma unroll
    for (int ct = 0; ct < 16; ++ct) {
        u32x4 bfr = Bg[((size_t)ntg * 16 + ct) * 64 + lane];
#pragma unroll
        for (int mt = 0; mt < 4; ++mt) {
            u32x4 afr = Ag[(((size_t)(i0 >> 4) + mt) * 16 + ct) * 64 + lane];
            acc[mt] = mfma16(afr, bfr, acc[mt]);
        }
    }
    float bv = bias[ntg * 16 + m];
#pragma unroll
    for (int mt = 0; mt < 4; ++mt) {
        int i = i0 + mt * 16 + q * 4;   // conv2 k-index (fc row)
        ushort4 o;
        o.x = f2bf((acc[mt][0] + bv) * dinv[i + 0]);
        o.y = f2bf((acc[mt][1] + bv) * dinv[i + 1]);
        o.z = f2bf((acc[mt][2] + bv) * dinv[i + 2]);
        o.w = f2bf((acc[mt][3] + bv) * dinv[i + 3]);
        size_t off = ((size_t)ntg * 256 + (i >> 5)) * 512
                   + (size_t)((i >> 3) & 3) * 128 + m * 8 + (q & 1) * 4;
        *(ushort4*)(fcF + off) = o;
    }
}

// ---------------- conv2: out = sigmoid(dvi * (adj @ fc2)) — frag-major GEMM ----------------
// M=8192 N=512 K=8192. Block 128 rows x 128 cols, 512 thr / 8 waves.
// Wave = (kg,rg,cg): 64x64 tile (R=4 x C=4 16x16 frags), kg halves split K (chunks 0..31 /
// 32..63), combined via one LDS f32 reduction. C=4 gives 4 MFMAs per A-frag LDS read:
// per barrier-iter (2 chunks) LDS = 128KB reads + 64KB DMA writes (~1850 cyc) vs
// MFMA 2064 cyc -> MFMA-bound (was C=1: 256KB/chunk -> 37% MfmaUtil, LDS-bound).
// A staged via global_load_lds width=16 (frag = wave-uniform base + lane*16, linear).
// B (fcF) kept in regs, prefetched 4 kt deep from L2/L3.
// Swizzle: 256 blocks, xcd=bid&7; iblk=(g>>2)*8+xcd -> the 4 cblk blocks of an iblk are
// co-resident on ONE xcd => A slice fetched from HBM once, L2 serves re-reads.
__global__ __launch_bounds__(512, 2) void conv2_kernel(const unsigned short* __restrict__ adjF,
                                                       const unsigned short* __restrict__ fcF,
                                                       const float* __restrict__ dinv,
                                                       float* __restrict__ out) {
    const int bid = blockIdx.x;
    const int xcd = bid & 7;
    const int g = bid >> 3;               // 0..31
    const int iblk = (g >> 2) * 8 + xcd;  // 0..63
    const int cblk = g & 3;
    const int i0 = iblk * 128;

    const int lane = threadIdx.x & 63;
    const int wave = threadIdx.x >> 6;    // 0..7
    const int kg = wave >> 2;             // K half: chunks [kg*32, kg*32+32)
    const int rg = (wave >> 1) & 1;       // row half (64 rows)
    const int cg = wave & 1;              // col half (64 cols)
    const int m = lane & 15, q = lane >> 4;
    const int nt0 = cblk * 8 + cg * 4;    // 4 B col-frags nt0..nt0+3
    const int itbase = i0 >> 4;
    const int sw = wave & 3;              // staging slot within kg group: it = sw*2+{0,1}

    __shared__ __align__(16) unsigned short Abuf[2][2][4][8][512];  // 128 KB [kg][buf][ktl][it][frag]

    const u32x4* Bg = (const u32x4*)fcF;
    // per-lane global src base for this wave's 8 staged frags (lane*8 ushorts = 16 B)
    const unsigned short* a0 = adjF + ((size_t)(itbase + sw * 2) * 256) * 512 + lane * 8;

    f32x4 acc[4][4] = {};
    u32x4 bq[4][4];

    const int kb0 = kg * 128;             // first kt of this wave's K half

    // prologue: DMA chunk 0 of this half into buf 0; preload B kt kb0..kb0+3
#pragma unroll
    for (int s = 0; s < 2; ++s)
#pragma unroll
        for (int ktl = 0; ktl < 4; ++ktl)
            glds16(a0 + ((size_t)s * 256 + kb0 + ktl) * 512, &Abuf[kg][0][ktl][sw * 2 + s][0]);
#pragma unroll
    for (int ktl = 0; ktl < 4; ++ktl)
#pragma unroll
        for (int ct = 0; ct < 4; ++ct)
            bq[ktl][ct] = Bg[((size_t)(nt0 + ct) * 256 + kb0 + ktl) * 64 + lane];
    __syncthreads();

    for (int c = 0; c < 32; ++c) {
        const int kb = kb0 + c * 4;
        const int cur = c & 1, nxt = cur ^ 1;
        // async-stage next chunk (buf[nxt] fully read last iter; barrier since)
        if (c < 31) {
            const int kbn = kb + 4;
#pragma unroll
            for (int s = 0; s < 2; ++s)
#pragma unroll
                for (int ktl = 0; ktl < 4; ++ktl)
                    glds16(a0 + ((size_t)s * 256 + kbn + ktl) * 512,
                           &Abuf[kg][nxt][ktl][sw * 2 + s][0]);
        }
#pragma unroll
        for (int ktl = 0; ktl < 4; ++ktl) {
            int ktn = kb + ktl + 4; if (ktn > 255) ktn = 255;
            u32x4 bn[4];
#pragma unroll
            for (int ct = 0; ct < 4; ++ct)
                bn[ct] = Bg[((size_t)(nt0 + ct) * 256 + ktn) * 64 + lane];
            u32x4 pa[4];
#pragma unroll
            for (int mt = 0; mt < 4; ++mt)
                pa[mt] = *(const u32x4*)&Abuf[kg][cur][ktl][rg * 4 + mt][lane * 8];
#pragma unroll
            for (int mt = 0; mt < 4; ++mt)
#pragma unroll
                for (int ct = 0; ct < 4; ++ct)
                    acc[mt][ct] = mfma16(pa[mt], bq[ktl][ct], acc[mt][ct]);
#pragma unroll
            for (int ct = 0; ct < 4; ++ct)
                bq[ktl][ct] = bn[ct];
        }
        __syncthreads();   // drains DMA for next chunk + fences buf[cur] reads
    }

    // cross-kg combine: kg1 publishes acc (f32, stride 132 to dodge bank conflicts),
    // kg0 adds + epilogue. Reuses Abuf (all reads fenced by final loop barrier).
    float* red = (float*)&Abuf[0][0][0][0][0];   // 128*132*4 = 67.6 KB < 128 KB
    if (kg == 1) {
#pragma unroll
        for (int mt = 0; mt < 4; ++mt)
#pragma unroll
            for (int ct = 0; ct < 4; ++ct)
#pragma unroll
                for (int r = 0; r < 4; ++r)
                    red[(rg * 64 + mt * 16 + q * 4 + r) * 132 + cg * 64 + ct * 16 + m] = acc[mt][ct][r];
    }
    __syncthreads();
    if (kg == 0) {
#pragma unroll
        for (int mt = 0; mt < 4; ++mt)
#pragma unroll
            for (int ct = 0; ct < 4; ++ct)
#pragma unroll
                for (int r = 0; r < 4; ++r) {
                    int lrow = rg * 64 + mt * 16 + q * 4 + r;
                    int row = i0 + lrow;
                    int lcol = cg * 64 + ct * 16 + m;
                    float v = acc[mt][ct][r] + red[lrow * 132 + lcol];
                    float xv = v * dinv[row];
                    out[(size_t)row * CDIM + cblk * 128 + lcol] = 1.0f / (1.0f + __expf(-xv));
                }
    }
}

extern "C" void kernel_launch(void* const* d_in, const int* in_sizes, int n_in,
                              void* d_out, int out_size, void* d_ws, size_t ws_size,
                              hipStream_t stream) {
    const float* bbn = (const float*)d_in[0];
    const float* cbn = (const float*)d_in[1];
    const float* W   = (const float*)d_in[2];
    const float* b   = (const float*)d_in[3];
    float* out = (float*)d_out;  // reference output is float32

    char* ws = (char*)d_ws;
    unsigned short* tbf  = (unsigned short*)(ws);                 // 1 MB
    float* s             = (float*)(ws + (1u << 20));             // 32 KB
    float* d             = (float*)(ws + (1u << 20) + 32768);     // 32 KB
    float* dinv          = (float*)(ws + (1u << 20) + 65536);     // 32 KB
    unsigned short* fcF  = (unsigned short*)(ws + (2u << 20));    // 8 MB
    unsigned short* cbnF = (unsigned short*)(ws + (10u << 20));   // 8 MB
    unsigned short* WF   = (unsigned short*)(ws + (18u << 20));   // 0.5 MB
    unsigned short* adjF = (unsigned short*)(ws + (19u << 20));   // 128 MiB

    prep_kernel<<<NN * 16 / 256, 256, 0, stream>>>(bbn, tbf, s);
    prep_cbn_kernel<<<512, 256, 0, stream>>>(cbn, cbnF);
    prep_w_kernel<<<128, 256, 0, stream>>>(W, WF);
    hipMemsetAsync(d, 0, NN * sizeof(float), stream);
    scoredeg_kernel<<<dim3(NN / 64, 16), 256, 0, stream>>>(tbf, s, d, adjF);
    dinv_kernel<<<NN / 256, 256, 0, stream>>>(d, dinv);
    fc_kernel<<<dim3(NN / 64, 8), 256, 0, stream>>>(cbnF, WF, b, dinv, fcF);
    conv2_kernel<<<256, 512, 0, stream>>>(adjF, fcF, dinv, out);
}